// Round 6
// baseline (293.288 us; speedup 1.0000x reference)
//
#include <hip/hip_runtime.h>

// GraphSAGE: 2x SAGEConv(mean) + ReLU, then linear out.
// N=40000, E=640000, IN=H=128, OUT=64. ALL-f32 (round-2 numerics, proven).
// Round 6: sage GEMM v2 — BK=64 (half the barriers), register prefetch of
// next K-tile (T14 async-stage: global latency hides under FMA), XOR-swizzled
// A-transpose in LDS (conflict-free writes+reads). Same summation order as
// round 5 (bit-identical output). agg/CSR/out_gemm unchanged from round 5.

__global__ __launch_bounds__(256) void k_hist(const int* __restrict__ dst,
                                              int* __restrict__ cnt, int E) {
  int e = blockIdx.x * 256 + threadIdx.x;
  if (e < E) atomicAdd(&cnt[dst[e]], 1);
}

// Per-1024-block sums of cnt -> blockSums[b]
__global__ __launch_bounds__(1024) void k_bsum(const int* __restrict__ cnt,
                                               int* __restrict__ blockSums, int N) {
  __shared__ int ws[16];
  int i = blockIdx.x * 1024 + threadIdx.x;
  int v = (i < N) ? cnt[i] : 0;
#pragma unroll
  for (int d = 32; d > 0; d >>= 1) v += __shfl_xor(v, d, 64);
  if ((threadIdx.x & 63) == 0) ws[threadIdx.x >> 6] = v;
  __syncthreads();
  if (threadIdx.x == 0) {
    int s = 0;
#pragma unroll
    for (int w = 0; w < 16; ++w) s += ws[w];
    blockSums[blockIdx.x] = s;
  }
}

// Tiny serial scan of nb block sums (nb=40) -> blockOff; rowptr[N]=total.
__global__ __launch_bounds__(64) void k_bscan(const int* __restrict__ blockSums,
                                              int* __restrict__ blockOff,
                                              int* __restrict__ rowptr, int nb, int N) {
  if (threadIdx.x == 0) {
    int run = 0;
    for (int i = 0; i < nb; ++i) {
      blockOff[i] = run;
      run += blockSums[i];
    }
    rowptr[N] = run;
  }
}

// Per-block exclusive scan of cnt + blockOff -> rowptr, cursor.
__global__ __launch_bounds__(1024) void k_escan(const int* __restrict__ cnt,
                                                const int* __restrict__ blockOff,
                                                int* __restrict__ rowptr,
                                                int* __restrict__ cursor, int N) {
  __shared__ int warpSums[16];
  const int tid = threadIdx.x;
  const int lane = tid & 63, wid = tid >> 6;
  int i = blockIdx.x * 1024 + tid;
  int v = (i < N) ? cnt[i] : 0;
  int s = v;
#pragma unroll
  for (int d = 1; d < 64; d <<= 1) {
    int t = __shfl_up(s, d, 64);
    if (lane >= d) s += t;
  }
  if (lane == 63) warpSums[wid] = s;
  __syncthreads();
  if (tid < 16) {
    int w = warpSums[tid];
#pragma unroll
    for (int d = 1; d < 16; d <<= 1) {
      int t = __shfl_up(w, d, 16);
      if (tid >= d) w += t;
    }
    warpSums[tid] = w;
  }
  __syncthreads();
  int ex = blockOff[blockIdx.x] + (wid ? warpSums[wid - 1] : 0) + s - v;
  if (i < N) {
    rowptr[i] = ex;
    cursor[i] = ex;
  }
}

__global__ __launch_bounds__(256) void k_fill(const int* __restrict__ src,
                                              const int* __restrict__ dst,
                                              int* __restrict__ cursor,
                                              int* __restrict__ csr_src, int E) {
  int e = blockIdx.x * 256 + threadIdx.x;
  if (e < E) {
    int pos = atomicAdd(&cursor[dst[e]], 1);
    csr_src[pos] = src[e];
  }
}

// One wave per node: mean of f32 neighbor rows (128 feats).
// 64 lanes x float2 per row; 4 rows in flight per iteration.
__global__ __launch_bounds__(256) void k_agg(const float* __restrict__ feat,
                                             const int* __restrict__ rowptr,
                                             const int* __restrict__ csr_src,
                                             float* __restrict__ agg, int N) {
  int node = (blockIdx.x * 256 + threadIdx.x) >> 6;
  if (node >= N) return;
  const int lane = threadIdx.x & 63;
  const int beg = rowptr[node];
  const int deg = rowptr[node + 1] - beg;
  const int c = lane * 2;
  float2 a0 = {0.f, 0.f}, a1 = {0.f, 0.f}, a2 = {0.f, 0.f}, a3 = {0.f, 0.f};
  int j = 0;
  for (; j + 3 < deg; j += 4) {
    int s0 = csr_src[beg + j + 0];
    int s1 = csr_src[beg + j + 1];
    int s2 = csr_src[beg + j + 2];
    int s3 = csr_src[beg + j + 3];
    float2 v0 = *reinterpret_cast<const float2*>(feat + (size_t)s0 * 128 + c);
    float2 v1 = *reinterpret_cast<const float2*>(feat + (size_t)s1 * 128 + c);
    float2 v2 = *reinterpret_cast<const float2*>(feat + (size_t)s2 * 128 + c);
    float2 v3 = *reinterpret_cast<const float2*>(feat + (size_t)s3 * 128 + c);
    a0.x += v0.x; a0.y += v0.y;
    a1.x += v1.x; a1.y += v1.y;
    a2.x += v2.x; a2.y += v2.y;
    a3.x += v3.x; a3.y += v3.y;
  }
  for (; j < deg; ++j) {
    int s0 = csr_src[beg + j];
    float2 v0 = *reinterpret_cast<const float2*>(feat + (size_t)s0 * 128 + c);
    a0.x += v0.x; a0.y += v0.y;
  }
  float invd = 1.0f / fmaxf((float)deg, 1.0f);
  float2 o;
  o.x = (a0.x + a1.x + a2.x + a3.x) * invd;
  o.y = (a0.y + a1.y + a2.y + a3.y) * invd;
  *reinterpret_cast<float2*>(agg + (size_t)node * 128 + c) = o;
}

// Fused SAGE layer: out = relu([agg | root] @ [Wl; Wr] + b)
// Tile: 64 nodes x 128 cols, 256 threads, each 8 nodes x 4 cols.
// BK=64 (4 K-steps), register prefetch of next tile, swizzled A-transpose.
// K order identical to round 5: agg k0..127 then root k0..127.
template <bool RELU>
__global__ __launch_bounds__(256) void k_sage_gemm(
    const float* __restrict__ agg, const float* __restrict__ root,
    const float* __restrict__ Wl, const float* __restrict__ Wr,
    const float* __restrict__ bias, float* __restrict__ out, int M) {
  __shared__ float A[64][64];    // [kk][node ^ swz(kk)]
  __shared__ float B[64][132];   // [kk][col]
  const int tid = threadIdx.x;
  const int tx = tid & 31;   // col group: cols tx*4 .. +3
  const int ty = tid >> 5;   // node group: nodes ty*8 .. +7
  const int m0 = blockIdx.x * 64;
  float acc[8][4] = {};
  float4 ra[4];
  float4 rb[8];

  // Prefetch step 0 (agg, k 0..63)
#pragma unroll
  for (int j = 0; j < 4; ++j) {
    int node = m0 + (tid >> 4) + 16 * j;
    if (node >= M) node = M - 1;
    ra[j] = *reinterpret_cast<const float4*>(agg + (size_t)node * 128 + (tid & 15) * 4);
  }
#pragma unroll
  for (int j = 0; j < 8; ++j) {
    int kk = (tid >> 5) + 8 * j;
    rb[j] = *reinterpret_cast<const float4*>(Wl + (size_t)kk * 128 + (tid & 31) * 4);
  }

  for (int step = 0; step < 4; ++step) {
    __syncthreads();   // previous step's LDS consumers done
    // Registers -> LDS
    {
      const int kkb = (tid & 15) * 4;
      const int swz = (tid & 7) << 2;   // ((kkb>>2)&7)<<2
#pragma unroll
      for (int j = 0; j < 4; ++j) {
        int nloc = ((tid >> 4) + 16 * j) ^ swz;
        A[kkb + 0][nloc] = ra[j].x;
        A[kkb + 1][nloc] = ra[j].y;
        A[kkb + 2][nloc] = ra[j].z;
        A[kkb + 3][nloc] = ra[j].w;
      }
#pragma unroll
      for (int j = 0; j < 8; ++j) {
        *reinterpret_cast<float4*>(&B[(tid >> 5) + 8 * j][(tid & 31) * 4]) = rb[j];
      }
    }
    __syncthreads();
    // Issue next tile's global loads (consumed after next barrier -> latency
    // hides under the FMA loop below).
    if (step < 3) {
      const int ns = step + 1;
      const float* Asrc = (ns < 2) ? agg : root;
      const float* W = (ns < 2) ? Wl : Wr;
      const int kb = (ns & 1) * 64;
#pragma unroll
      for (int j = 0; j < 4; ++j) {
        int node = m0 + (tid >> 4) + 16 * j;
        if (node >= M) node = M - 1;
        ra[j] = *reinterpret_cast<const float4*>(Asrc + (size_t)node * 128 + kb + (tid & 15) * 4);
      }
#pragma unroll
      for (int j = 0; j < 8; ++j) {
        int kk = (tid >> 5) + 8 * j;
        rb[j] = *reinterpret_cast<const float4*>(W + (size_t)(kb + kk) * 128 + (tid & 31) * 4);
      }
    }
    // Compute from LDS
#pragma unroll 8
    for (int kk = 0; kk < 64; ++kk) {
      const int swz = ((kk >> 2) & 7) << 2;
      float4 b4 = *reinterpret_cast<float4*>(&B[kk][tx * 4]);
      float4 a0 = *reinterpret_cast<float4*>(&A[kk][(ty * 8) ^ swz]);
      float4 a1 = *reinterpret_cast<float4*>(&A[kk][(ty * 8 + 4) ^ swz]);
      float a[8] = {a0.x, a0.y, a0.z, a0.w, a1.x, a1.y, a1.z, a1.w};
#pragma unroll
      for (int i = 0; i < 8; ++i) {
        acc[i][0] = fmaf(a[i], b4.x, acc[i][0]);
        acc[i][1] = fmaf(a[i], b4.y, acc[i][1]);
        acc[i][2] = fmaf(a[i], b4.z, acc[i][2]);
        acc[i][3] = fmaf(a[i], b4.w, acc[i][3]);
      }
    }
  }

  float4 bv = *reinterpret_cast<const float4*>(bias + tx * 4);
#pragma unroll
  for (int i = 0; i < 8; ++i) {
    int node = m0 + ty * 8 + i;
    if (node >= M) continue;
    float4 r;
    r.x = acc[i][0] + bv.x;
    r.y = acc[i][1] + bv.y;
    r.z = acc[i][2] + bv.z;
    r.w = acc[i][3] + bv.w;
    if (RELU) {
      r.x = fmaxf(r.x, 0.f); r.y = fmaxf(r.y, 0.f);
      r.z = fmaxf(r.z, 0.f); r.w = fmaxf(r.w, 0.f);
    }
    *reinterpret_cast<float4*>(out + (size_t)node * 128 + tx * 4) = r;
  }
}

// out = h @ Wout + bout ; tile 64 nodes x 64 cols, each thread 4x4. (proven)
__global__ __launch_bounds__(256) void k_out_gemm(
    const float* __restrict__ h, const float* __restrict__ Wout,
    const float* __restrict__ bias, float* __restrict__ out, int M) {
  __shared__ float A[32][68];
  __shared__ float B[32][68];
  const int tid = threadIdx.x;
  const int tx = tid & 15;
  const int ty = tid >> 4;
  const int m0 = blockIdx.x * 64;
  float acc[4][4] = {};
  for (int k0 = 0; k0 < 128; k0 += 32) {
    __syncthreads();
#pragma unroll
    for (int j = 0; j < 2; ++j) {
      int idx = tid + j * 256;
      int r = idx >> 3;
      int c = (idx & 7) << 2;
      int node = m0 + r;
      if (node >= M) node = M - 1;
      float4 v = *reinterpret_cast<const float4*>(h + (size_t)node * 128 + k0 + c);
      A[c + 0][r] = v.x; A[c + 1][r] = v.y; A[c + 2][r] = v.z; A[c + 3][r] = v.w;
    }
#pragma unroll
    for (int j = 0; j < 2; ++j) {
      int idx = tid + j * 256;
      int kk = idx >> 4;
      int c = (idx & 15) << 2;
      float4 v = *reinterpret_cast<const float4*>(Wout + (size_t)(k0 + kk) * 64 + c);
      *reinterpret_cast<float4*>(&B[kk][c]) = v;
    }
    __syncthreads();
#pragma unroll 8
    for (int kk = 0; kk < 32; ++kk) {
      float4 b4 = *reinterpret_cast<float4*>(&B[kk][tx * 4]);
      float4 a4 = *reinterpret_cast<float4*>(&A[kk][ty * 4]);
      float a[4] = {a4.x, a4.y, a4.z, a4.w};
#pragma unroll
      for (int i = 0; i < 4; ++i) {
        acc[i][0] = fmaf(a[i], b4.x, acc[i][0]);
        acc[i][1] = fmaf(a[i], b4.y, acc[i][1]);
        acc[i][2] = fmaf(a[i], b4.z, acc[i][2]);
        acc[i][3] = fmaf(a[i], b4.w, acc[i][3]);
      }
    }
  }
  float4 bv = *reinterpret_cast<const float4*>(bias + tx * 4);
#pragma unroll
  for (int i = 0; i < 4; ++i) {
    int node = m0 + ty * 4 + i;
    if (node >= M) continue;
    float4 r;
    r.x = acc[i][0] + bv.x;
    r.y = acc[i][1] + bv.y;
    r.z = acc[i][2] + bv.z;
    r.w = acc[i][3] + bv.w;
    *reinterpret_cast<float4*>(out + (size_t)node * 64 + tx * 4) = r;
  }
}

extern "C" void kernel_launch(void* const* d_in, const int* in_sizes, int n_in,
                              void* d_out, int out_size, void* d_ws, size_t ws_size,
                              hipStream_t stream) {
  const float* x    = (const float*)d_in[0];
  const int*   ei   = (const int*)d_in[1];
  const float* W1l  = (const float*)d_in[2];
  const float* W1r  = (const float*)d_in[3];
  const float* b1   = (const float*)d_in[4];
  const float* W2l  = (const float*)d_in[5];
  const float* W2r  = (const float*)d_in[6];
  const float* b2   = (const float*)d_in[7];
  const float* Wout = (const float*)d_in[8];
  const float* bout = (const float*)d_in[9];
  float* out = (float*)d_out;

  const int N = in_sizes[0] / 128;
  const int E = in_sizes[1] / 2;
  const int* src = ei;
  const int* dst = ei + E;

  // Workspace layout byte-identical to round 2 (proven fit).
  auto align = [](size_t b) { return (b + 255) & ~(size_t)255; };
  char* p = (char*)d_ws;
  int* cnt     = (int*)p;   p += align((size_t)N * 4);
  int* rowptr  = (int*)p;   p += align((size_t)(N + 1) * 4);
  int* cursor  = (int*)p;   p += align((size_t)N * 4);
  int* csr_src = (int*)p;   p += align((size_t)E * 4);
  float* bufA  = (float*)p; p += (size_t)N * 128 * 4;
  float* bufB  = (float*)p;
  // Scan scratch lives in bufA's head (dead until k_agg overwrites it).
  int* blockSums = (int*)bufA;
  int* blockOff  = blockSums + 64;

  hipMemsetAsync(cnt, 0, (size_t)N * 4, stream);

  const int nb = (N + 1023) / 1024;  // 40
  const int gemmBlocks = (N + 63) / 64;
  const int aggBlocks = (N + 3) / 4;

  // CSR build: hist -> parallel scan -> fill
  k_hist<<<(E + 255) / 256, 256, 0, stream>>>(dst, cnt, E);
  k_bsum<<<nb, 1024, 0, stream>>>(cnt, blockSums, N);
  k_bscan<<<1, 64, 0, stream>>>(blockSums, blockOff, rowptr, nb, N);
  k_escan<<<nb, 1024, 0, stream>>>(cnt, blockOff, rowptr, cursor, N);
  k_fill<<<(E + 255) / 256, 256, 0, stream>>>(src, dst, cursor, csr_src, E);

  // Layer 1
  k_agg<<<aggBlocks, 256, 0, stream>>>(x, rowptr, csr_src, bufA, N);
  k_sage_gemm<true><<<gemmBlocks, 256, 0, stream>>>(bufA, x, W1l, W1r, b1, bufB, N);

  // Layer 2
  k_agg<<<aggBlocks, 256, 0, stream>>>(bufB, rowptr, csr_src, bufA, N);
  k_sage_gemm<true><<<gemmBlocks, 256, 0, stream>>>(bufA, bufB, W2l, W2r, b2, bufB, N);

  // Output projection
  k_out_gemm<<<gemmBlocks, 256, 0, stream>>>(bufB, Wout, bout, out, N);
}